// Round 1
// baseline (67.164 us; speedup 1.0000x reference)
//
#include <hip/hip_runtime.h>

// Unsharp-mask filter: out = img + param * (img - gaussblur25(img)), param = 5*(tanh(f[b,0])*.5+.5)
// img: (16,3,512,512) fp32, features: (16,8) fp32.
// Output: [out (12582912 fp32)] ++ [param (16 fp32)].
//
// Separable 25-tap Gaussian (sigma=5), reflect padding. Fused single kernel:
// 64x64 output tile per block, 88x88 padded input tile staged in LDS,
// horizontal pass -> 88x64 LDS temp, vertical pass + epilogue fused.

#define RADIUS 12
#define KSIZE  25
#define TILE   64
#define PT     (TILE + 2 * RADIUS)   // 88
#define IMG_W  512
#define IMG_H  512

__global__ __launch_bounds__(256) void usm_kernel(
    const float* __restrict__ img,
    const float* __restrict__ feat,
    float* __restrict__ out,
    float* __restrict__ out_param)
{
    __shared__ float tileA[PT][PT];    // 88x88 padded input tile (30.25 KB)
    __shared__ float tmpB[PT][TILE];   // 88x64 horizontally-blurred (22 KB)

    const int tid = threadIdx.x;
    const int tx0 = blockIdx.x * TILE;
    const int ty0 = blockIdx.y * TILE;
    const int zc  = blockIdx.z;        // b*3 + c
    const int b   = zc / 3;

    // Normalized Gaussian weights (sigma=5, radius=12), computed per-thread.
    float w[KSIZE];
    float s = 0.f;
#pragma unroll
    for (int i = 0; i < KSIZE; ++i) {
        float x = (float)(i - RADIUS) * 0.2f;   // /sigma
        w[i] = expf(-0.5f * x * x);
        s += w[i];
    }
    const float inv = 1.0f / s;
#pragma unroll
    for (int i = 0; i < KSIZE; ++i) w[i] *= inv;

    const float param = (tanhf(feat[b * 8]) * 0.5f + 0.5f) * 5.0f;

    const float* __restrict__ src = img + (size_t)zc * IMG_W * IMG_H;

    // ---- Stage padded 88x88 tile into LDS (reflect indexing at borders) ----
    for (int li = tid; li < PT * PT; li += 256) {
        int py = li / PT;
        int px = li - py * PT;
        int gy = ty0 - RADIUS + py;
        int gx = tx0 - RADIUS + px;
        gy = (gy < 0) ? -gy : ((gy >= IMG_H) ? (2 * IMG_H - 2 - gy) : gy);
        gx = (gx < 0) ? -gx : ((gx >= IMG_W) ? (2 * IMG_W - 2 - gx) : gx);
        tileA[py][px] = src[gy * IMG_W + gx];
    }
    __syncthreads();

    // ---- Horizontal 25-tap pass: 88 rows x 64 cols ----
    for (int li = tid; li < PT * TILE; li += 256) {
        int py = li >> 6;
        int ox = li & 63;
        float acc = 0.f;
#pragma unroll
        for (int k = 0; k < KSIZE; ++k) acc += w[k] * tileA[py][ox + k];
        tmpB[py][ox] = acc;
    }
    __syncthreads();

    // ---- Vertical 25-tap pass + fused unsharp epilogue ----
    float* __restrict__ dst = out + (size_t)zc * IMG_W * IMG_H;
    for (int li = tid; li < TILE * TILE; li += 256) {
        int oy = li >> 6;
        int ox = li & 63;
        float acc = 0.f;
#pragma unroll
        for (int k = 0; k < KSIZE; ++k) acc += w[k] * tmpB[oy + k][ox];
        float v = tileA[oy + RADIUS][ox + RADIUS];
        dst[(ty0 + oy) * IMG_W + tx0 + ox] = v + param * (v - acc);
    }

    // ---- param output (16 floats appended after the image) ----
    if (tid == 0 && blockIdx.x == 0 && blockIdx.y == 0 && (zc - b * 3) == 0)
        out_param[b] = param;
}

extern "C" void kernel_launch(void* const* d_in, const int* in_sizes, int n_in,
                              void* d_out, int out_size, void* d_ws, size_t ws_size,
                              hipStream_t stream) {
    const float* img  = (const float*)d_in[0];   // 16*3*512*512
    const float* feat = (const float*)d_in[1];   // 16*8
    float* out       = (float*)d_out;
    float* out_param = (float*)d_out + (size_t)16 * 3 * IMG_W * IMG_H;

    dim3 grid(IMG_W / TILE, IMG_H / TILE, 16 * 3);   // 8 x 8 x 48
    dim3 block(256);
    usm_kernel<<<grid, block, 0, stream>>>(img, feat, out, out_param);
}

// Round 2
// 58.559 us; speedup vs baseline: 1.1469x; 1.1469x over previous
//
#include <hip/hip_runtime.h>

// Unsharp-mask: out = img + param * (img - gaussblur25(img)), param = 5*(tanh(f[b,0])*.5+.5)
// img: (16,3,512,512) fp32. Output: [out (12582912 fp32)] ++ [param (16 fp32)].
//
// Separable Gaussian, reflect pad. Register-blocked passes with ds_read_b128:
//   horizontal: 8 outputs/slot from 32 floats (8 float4 reads)
//   vertical:   4x4 micro-tile/thread from 28 float4 row reads

#define RADIUS 12
#define KS     25
#define TILE   64
#define PT     (TILE + 2 * RADIUS)   // 88
#define IMG_W  512
#define IMG_H  512

__device__ __forceinline__ int reflect512(int i) {
    i = (i < 0) ? -i : i;
    return (i >= 512) ? (1022 - i) : i;
}

__global__ __launch_bounds__(256) void usm_kernel(
    const float* __restrict__ img,
    const float* __restrict__ feat,
    float* __restrict__ out,
    float* __restrict__ out_param)
{
    __shared__ float tileA[PT][PT];    // 88x88 padded input (30.98 KB)
    __shared__ float tmpB[PT][TILE];   // 88x64 h-blurred    (22.53 KB)

    const int tid = threadIdx.x;
    const int tx0 = blockIdx.x * TILE;
    const int ty0 = blockIdx.y * TILE;
    const int zc  = blockIdx.z;        // b*3 + c
    const int b   = zc / 3;

    // Normalized Gaussian weights (sigma=5, radius=12)
    float w[KS];
    {
        float s = 0.f;
#pragma unroll
        for (int i = 0; i < KS; ++i) {
            float x = (float)(i - RADIUS) * 0.2f;
            w[i] = __expf(-0.5f * x * x);
            s += w[i];
        }
        const float inv = 1.0f / s;
#pragma unroll
        for (int i = 0; i < KS; ++i) w[i] *= inv;
    }

    const float param = (tanhf(feat[b * 8]) * 0.5f + 0.5f) * 5.0f;
    const float* __restrict__ src = img + (size_t)zc * IMG_W * IMG_H;

    // ---- Stage 88x88 padded tile (float4 slots; x-reflect only on edge tiles) ----
    const bool xedge = (blockIdx.x == 0) || (blockIdx.x == 7);
    for (int li = tid; li < PT * (PT / 4); li += 256) {   // 88*22 = 1936 slots
        int py = li / 22;
        int x4 = li - py * 22;
        int gy = reflect512(ty0 - RADIUS + py);
        const float* rowp = src + gy * IMG_W;
        int gx = tx0 - RADIUS + x4 * 4;
        float4 v;
        if (!xedge) {
            v = *(const float4*)(rowp + gx);
        } else {
            v.x = rowp[reflect512(gx)];
            v.y = rowp[reflect512(gx + 1)];
            v.z = rowp[reflect512(gx + 2)];
            v.w = rowp[reflect512(gx + 3)];
        }
        *(float4*)&tileA[py][x4 * 4] = v;
    }
    __syncthreads();

    // ---- Horizontal: 88 rows x 8 groups of 8 outputs = 704 slots ----
    for (int li = tid; li < PT * (TILE / 8); li += 256) {
        int py = li >> 3;
        int g  = li & 7;
        float r[32];
#pragma unroll
        for (int i = 0; i < 8; ++i)
            *(float4*)&r[4 * i] = *(const float4*)&tileA[py][g * 8 + 4 * i];
        float acc[8];
#pragma unroll
        for (int o = 0; o < 8; ++o) {
            float a = 0.f;
#pragma unroll
            for (int k = 0; k < KS; ++k) a += w[k] * r[o + k];
            acc[o] = a;
        }
        *(float4*)&tmpB[py][g * 8]     = make_float4(acc[0], acc[1], acc[2], acc[3]);
        *(float4*)&tmpB[py][g * 8 + 4] = make_float4(acc[4], acc[5], acc[6], acc[7]);
    }
    __syncthreads();

    // ---- Vertical + epilogue: 4x4 micro-tile per thread (16x16 thread map) ----
    const int tx4 = (tid & 15) * 4;      // column group (4 floats)
    const int ry0 = (tid >> 4) * 4;      // first output row of micro-tile
    float ax[4], ay[4], az[4], aw[4];
#pragma unroll
    for (int d = 0; d < 4; ++d) { ax[d] = ay[d] = az[d] = aw[d] = 0.f; }

#pragma unroll
    for (int k = 0; k < KS + 3; ++k) {   // 28 row reads
        float4 t = *(const float4*)&tmpB[ry0 + k][tx4];
#pragma unroll
        for (int d = 0; d < 4; ++d) {
            int kk = k - d;
            if (kk >= 0 && kk < KS) {
                float wk = w[kk];
                ax[d] += wk * t.x; ay[d] += wk * t.y;
                az[d] += wk * t.z; aw[d] += wk * t.w;
            }
        }
    }

    float* __restrict__ dst = out + (size_t)zc * IMG_W * IMG_H;
#pragma unroll
    for (int d = 0; d < 4; ++d) {
        int oy = ry0 + d;
        float4 v = *(const float4*)&tileA[oy + RADIUS][tx4 + RADIUS];
        float4 o;
        o.x = v.x + param * (v.x - ax[d]);
        o.y = v.y + param * (v.y - ay[d]);
        o.z = v.z + param * (v.z - az[d]);
        o.w = v.w + param * (v.w - aw[d]);
        *(float4*)&dst[(size_t)(ty0 + oy) * IMG_W + tx0 + tx4] = o;
    }

    if (tid == 0 && blockIdx.x == 0 && blockIdx.y == 0 && (zc - b * 3) == 0)
        out_param[b] = param;
}

extern "C" void kernel_launch(void* const* d_in, const int* in_sizes, int n_in,
                              void* d_out, int out_size, void* d_ws, size_t ws_size,
                              hipStream_t stream) {
    const float* img  = (const float*)d_in[0];
    const float* feat = (const float*)d_in[1];
    float* out       = (float*)d_out;
    float* out_param = (float*)d_out + (size_t)16 * 3 * IMG_W * IMG_H;

    dim3 grid(IMG_W / TILE, IMG_H / TILE, 16 * 3);   // 8 x 8 x 48
    dim3 block(256);
    usm_kernel<<<grid, block, 0, stream>>>(img, feat, out, out_param);
}